// Round 1
// baseline (90.564 us; speedup 1.0000x reference)
//
#include <hip/hip_runtime.h>
#include <hip/hip_bf16.h>
#if !__has_builtin(__builtin_amdgcn_cvt_pk_fp8_f32)
#include <hip/hip_fp8.h>
#endif

typedef unsigned char u8;
typedef float f32x4 __attribute__((ext_vector_type(4)));
typedef int v8i __attribute__((ext_vector_type(8)));
typedef __attribute__((address_space(1))) const void* gas_p;
typedef __attribute__((address_space(3))) void* las_p;

#define NROW 8192
#define NHALF 4096
#define DIM 256
#define TILES 64                       // 8192 / 128
#define NBLK (TILES * (TILES + 1) / 2) // 2080 upper-triangular tiles
#define PBLK 512                       // k_prep blocks (one 16-row strip each)

// gbuf float offsets:
#define G_COL 0    // [0..255] column sums (atomic)
#define G_SS 256   // sum of |x|^2 (atomic)
#define G_CNT1 260 // k_mid completion counter (unsigned)
#define G_C4 272   // bandwidth scalar (scal = gbuf+G_C4)
#define G_ACC 288  // 32 accumulator slots, 16 floats apart

static __device__ __forceinline__ float fast_exp2(float x) {
#if __has_builtin(__builtin_amdgcn_exp2f)
  return __builtin_amdgcn_exp2f(x);
#else
  return exp2f(x);
#endif
}

// pack 4 floats -> 4 OCP e4m3 bytes (RNE, saturating) [k ascending in bytes]
static __device__ __forceinline__ unsigned pack4_fp8(float4 v) {
#if __has_builtin(__builtin_amdgcn_cvt_pk_fp8_f32)
  int p = 0;
  p = __builtin_amdgcn_cvt_pk_fp8_f32(v.x, v.y, p, false); // bytes 0,1
  p = __builtin_amdgcn_cvt_pk_fp8_f32(v.z, v.w, p, true);  // bytes 2,3
  return (unsigned)p;
#else
  __hip_fp8_e4m3 a(v.x), b(v.y), c(v.z), d(v.w);
  return (unsigned)a.__x | ((unsigned)b.__x << 8) | ((unsigned)c.__x << 16) |
         ((unsigned)d.__x << 24);
#endif
}

// Chunked K=128-fragment fp8 layout. Element (row r, k):
//   strip s = r>>4, frag f = k>>7, half h2 = (k>>4)&1, group g = (k>>5)&3
//   chunk = s*4 + f*2 + h2   (1 KiB chunks, 2048 total = 2 MiB)
//   byte  = chunk*1024 + (g*16 + (r&15))*16 + (k&15)
// A wave reading chunk base + lane*16 (dwordx4) is fully contiguous (1 KiB),
// and lane L = g*16 + row holds k in [g*32, g*32+32) split lo/hi 16B across
// the chunk pair -> exactly one v8i operand of mfma_scale 16x16x128 per frag.
// A and B read IDENTICAL bytes, so any within-block k-permutation cancels.

// ---------------- K1: fp32->fp8 chunked store + row |x|^2 + col partials ----
__global__ void k_prep(const float* __restrict__ src, const float* __restrict__ tgt,
                       u8* __restrict__ Xq, float* __restrict__ sq,
                       float* __restrict__ colpart, float* __restrict__ gbuf) {
  __shared__ float cps[4][DIM];
  int w = threadIdx.x >> 6, lane = threadIdx.x & 63;
  int s = blockIdx.x;
  int cc = threadIdx.x;
  if (s == 0) { // zero shared state (k_prep completes before k_mid launches)
    if (cc <= G_SS) atomicExch(gbuf + cc, 0.f);
    if (cc == 0) atomicExch(gbuf + G_SS, 0.f);
    if (cc == 0) atomicExch((unsigned*)(gbuf + G_CNT1), 0u);
    if (cc < 32) atomicExch(gbuf + G_ACC + cc * 16, 0.f);
  }
  int r0 = s * 16 + w * 4;
  // this lane covers k in [4*lane, 4*lane+4)
  int f = lane >> 5, h2 = (lane >> 2) & 1, g = (lane >> 3) & 3, j4 = (lane & 3) << 2;
  float4 ca = make_float4(0.f, 0.f, 0.f, 0.f);
#pragma unroll
  for (int rr = 0; rr < 4; ++rr) {
    int row = r0 + rr;
    const float* pp = (row < NHALF) ? (src + (size_t)row * DIM)
                                    : (tgt + (size_t)(row - NHALF) * DIM);
    float4 v = *(const float4*)(pp + lane * 4);
    size_t di = ((size_t)(s * 4 + f * 2 + h2) << 10) +
                ((g * 16 + (row & 15)) << 4) + j4;
    *(unsigned*)(Xq + di) = pack4_fp8(v);
    ca.x += v.x; ca.y += v.y; ca.z += v.z; ca.w += v.w;
    float sum = v.x * v.x + v.y * v.y + v.z * v.z + v.w * v.w;
#pragma unroll
    for (int off = 32; off > 0; off >>= 1) sum += __shfl_down(sum, off);
    if (lane == 0) sq[row] = sum;
  }
  cps[w][lane * 4 + 0] = ca.x;
  cps[w][lane * 4 + 1] = ca.y;
  cps[w][lane * 4 + 2] = ca.z;
  cps[w][lane * 4 + 3] = ca.w;
  __syncthreads();
  colpart[blockIdx.x * DIM + cc] = cps[0][cc] + cps[1][cc] + cps[2][cc] + cps[3][cc];
}

// ---------------- K2: fold partials + bandwidth scalar ----------------------
__global__ void k_mid(const float* __restrict__ colpart, const float* __restrict__ sq,
                      float* __restrict__ gbuf) {
  int b = blockIdx.x, c = threadIdx.x, lane = c & 63, w = c >> 6;
  __shared__ float rs[4];
  __shared__ unsigned oldc;
  float s = 0.f;
#pragma unroll
  for (int i = 0; i < 16; ++i) s += colpart[(size_t)(b * 16 + i) * DIM + c];
  atomicAdd(gbuf + G_COL + c, s); // 32-deep per column
  float qv = sq[b * DIM + c];
#pragma unroll
  for (int off = 32; off > 0; off >>= 1) qv += __shfl_down(qv, off);
  if (lane == 0) rs[w] = qv;
  __syncthreads();
  if (c == 0) {
    atomicAdd(gbuf + G_SS, rs[0] + rs[1] + rs[2] + rs[3]);
    __threadfence(); // order the adds before the counter
    oldc = atomicAdd((unsigned*)(gbuf + G_CNT1), 1u);
  }
  __syncthreads();
  if (oldc == 31) { // last block: compute c4 (block-uniform branch)
    float v = atomicAdd(gbuf + G_COL + c, 0.f); // coherent colsum read
    float vn = v * v;
#pragma unroll
    for (int off = 32; off > 0; off >>= 1) vn += __shfl_down(vn, off);
    __syncthreads(); // rs reuse
    if (lane == 0) rs[w] = vn;
    __syncthreads();
    if (c == 0) {
      double VN = (double)rs[0] + rs[1] + rs[2] + rs[3];
      double S  = (double)atomicAdd(gbuf + G_SS, 0.f);
      double suml2 = 2.0 * (double)NROW * S - 2.0 * VN;
      double bw = suml2 / ((double)NROW * NROW - NROW) / 4.0; // / 2^(KN/2)
      gbuf[G_C4] = (float)(1.4426950408889634 / (bw * 16.0)); // cross-kernel
    }
  }
}

// ---------------- K3: LDS-staged MX-fp8 X*X^T + multi-RBF + signed reduce ---
// 2080 blocks (upper-tri 128x128 tiles) x 256 threads (4 waves, 2x2 of 64x64).
// Per K-half f: stage 32 KiB (8 A-strips + 8 B-strips) via global_load_lds
// (halves L2 traffic vs direct loads: each strip fetched once per block),
// then 16 x mfma_scale_f32_16x16x128_f8f6f4 per wave (unit scales = fp8 GEMM
// at the 2x MX rate).
__global__ __launch_bounds__(256, 3) void k_main(const u8* __restrict__ Xq,
                                                 const float* __restrict__ sq,
                                                 const float* __restrict__ scal,
                                                 float* __restrict__ accbuf) {
  __shared__ u8 stage[32768]; // 32 x 1 KiB chunks: A = [0,16), B = [16,32)
  __shared__ float red[4];

  // linear triangle index -> (bi, bj), bj >= bi
  int bi = 0, rem = blockIdx.x;
  while (rem >= TILES - bi) { rem -= TILES - bi; ++bi; }
  int bj = bi + rem;

  int tid = threadIdx.x;
  int w = tid >> 6, lane = tid & 63;
  int wi = w >> 1, wj = w & 1;

  f32x4 acc[4][4];
#pragma unroll
  for (int a = 0; a < 4; ++a)
#pragma unroll
    for (int b = 0; b < 4; ++b) acc[a][b] = (f32x4){0.f, 0.f, 0.f, 0.f};

#pragma unroll
  for (int f = 0; f < 2; ++f) {
    // stage this K-half: 32 chunks, 8 per wave, each 64 lanes x 16 B (linear)
#pragma unroll
    for (int i = 0; i < 8; ++i) {
      int c = w + i * 4;
      int ii = c & 15;
      int bb = (c < 16) ? bi : bj;
      int gchunk = (bb * 8 + (ii >> 1)) * 4 + f * 2 + (ii & 1);
      const u8* g = Xq + ((size_t)gchunk << 10) + lane * 16;
      __builtin_amdgcn_global_load_lds((gas_p)g, (las_p)(stage + (c << 10)),
                                       16, 0, 0);
    }
    __syncthreads(); // vmcnt(0) drain + barrier: tile resident for all waves

    v8i aV[4], bV[4];
#pragma unroll
    for (int mi = 0; mi < 4; ++mi) {
      const u8* base = stage + ((wi * 4 + mi) << 11) + lane * 16;
      int4 lo = *(const int4*)(base);        // ds_read_b128, lane*16: no conflict
      int4 hi = *(const int4*)(base + 1024);
      aV[mi] = (v8i){lo.x, lo.y, lo.z, lo.w, hi.x, hi.y, hi.z, hi.w};
    }
#pragma unroll
    for (int ni = 0; ni < 4; ++ni) {
      const u8* base = stage + 16384 + ((wj * 4 + ni) << 11) + lane * 16;
      int4 lo = *(const int4*)(base);
      int4 hi = *(const int4*)(base + 1024);
      bV[ni] = (v8i){lo.x, lo.y, lo.z, lo.w, hi.x, hi.y, hi.z, hi.w};
    }
#pragma unroll
    for (int mi = 0; mi < 4; ++mi)
#pragma unroll
      for (int ni = 0; ni < 4; ++ni)
        acc[mi][ni] = __builtin_amdgcn_mfma_scale_f32_16x16x128_f8f6f4(
            aV[mi], bV[ni], acc[mi][ni], 0 /*fp8 A*/, 0 /*fp8 B*/,
            0, 0x7f7f7f7f, 0, 0x7f7f7f7f); // E8M0 0x7f == 1.0 scales
    __syncthreads(); // all LDS reads done before next-half restage
  }

  // Epilogue: l2 -> t + t^2 + t^4 + t^8 + t^16, signed sum.
  // C/D layout: col = lane&15, row = (lane>>4)*4 + reg (shape-determined).
  float c4 = scal[0];
  float c2 = 2.f * c4;
  float wgt = ((bi < 32) == (bj < 32)) ? 1.f : -1.f; // quadrant sign s_i*s_j
  if (bi != bj) wgt *= 2.f;                          // symmetry: count (j,i) too
  bool diag = (bi == bj);
  int ib = bi * 128 + wi * 64 + (lane >> 4) * 4;
  int jb = bj * 128 + wj * 64 + (lane & 15);
  f32x4 sic[4]; // -c4 * |x_i|^2 (hoisted: arg = fma(acc, 2c4, sic+sjc))
#pragma unroll
  for (int mi = 0; mi < 4; ++mi) {
    f32x4 q = *(const f32x4*)(sq + ib + mi * 16);
    sic[mi] = q * (-c4);
  }
  float lsum = 0.f;
#pragma unroll
  for (int ni = 0; ni < 4; ++ni) {
    float sjc = sq[jb + ni * 16] * (-c4);
#pragma unroll
    for (int mi = 0; mi < 4; ++mi) {
#pragma unroll
      for (int r = 0; r < 4; ++r) {
        float t  = fast_exp2(__builtin_fmaf(acc[mi][ni][r], c2, sic[mi][r] + sjc));
        float t2 = t * t, t4 = t2 * t2, t8 = t4 * t4, t16 = t8 * t8;
        float tt = t + t2 + t4 + t8 + t16;
        // exact diagonal: K_ii = 5 (kills fp8 quantization bias on l2_ii)
        if (diag && (ib + mi * 16 + r) == (jb + ni * 16)) tt = 5.f;
        lsum += tt;
      }
    }
  }
#pragma unroll
  for (int off = 32; off > 0; off >>= 1) lsum += __shfl_down(lsum, off);
  if (lane == 0) red[w] = lsum;
  __syncthreads();
  if (tid == 0)
    atomicAdd(accbuf + (blockIdx.x & 31) * 16,
              wgt * (red[0] + red[1] + red[2] + red[3]));
}

// ---------------- K4: finalize ----------------------------------------------
__global__ void k_fin(const float* __restrict__ accbuf, float* __restrict__ out) {
  int lane = threadIdx.x & 63;
  float s = (lane < 32) ? accbuf[lane * 16] : 0.f;
#pragma unroll
  for (int off = 32; off > 0; off >>= 1) s += __shfl_down(s, off);
  if (threadIdx.x == 0) out[0] = s / 16777216.f; // / 4096^2
}

extern "C" void kernel_launch(void* const* d_in, const int* in_sizes, int n_in,
                              void* d_out, int out_size, void* d_ws, size_t ws_size,
                              hipStream_t stream) {
  const float* src = (const float*)d_in[0];
  const float* tgt = (const float*)d_in[1];
  char* ws = (char*)d_ws;
  u8* Xq = (u8*)ws;                                      // 2 MiB chunked fp8
  size_t off = (size_t)NROW * DIM;
  float* sq = (float*)(ws + off);      off += NROW * 4;  // 32 KiB row |x|^2
  float* colpart = (float*)(ws + off); off += (size_t)PBLK * DIM * 4; // 512 KiB
  float* gbuf = (float*)(ws + off);    // colsum/ss/counter/c4/acc slots
  float* out = (float*)d_out;

  k_prep<<<PBLK, 256, 0, stream>>>(src, tgt, Xq, sq, colpart, gbuf);
  k_mid<<<32, 256, 0, stream>>>(colpart, sq, gbuf);
  k_main<<<NBLK, 256, 0, stream>>>(Xq, sq, gbuf + G_C4, gbuf + G_ACC);
  k_fin<<<1, 64, 0, stream>>>(gbuf + G_ACC, out);
}